// Round 1
// baseline (504.575 us; speedup 1.0000x reference)
//
#include <hip/hip_runtime.h>
#include <math.h>

// Problem constants (from reference setup_inputs)
#define BB 16
#define CC 192
#define KK 3
#define HH 48
#define WW 48
#define HW (HH * WW)                 // 2304
#define N_Y (BB * CC * HW)           // 7,077,888
#define IMG 768
#define N_X (BB * 3 * IMG * IMG)     // 28,311,552
#define N_Z (BB * CC * 12 * 12)      // 442,368
#define NUM_PIXELS (BB * IMG * IMG)  // 9,437,184

#define INV_SQRT2 0.7071067811865476f

// Fused grid partition (256 threads/block)
// GMM: 4 elements/thread (ONE float4 row) so that all 10 independent float4
// loads (y + 9 param planes) fit in registers and issue before any waitcnt.
// Prior 8-elem/thread version reported VGPR_Count=36 -> compiler serialized
// the 20-load batch; latency-bound at 21% HBM.
#define G_GMM   (N_Y / (256 * 4))    // 6912
#define G_MSE   1728                 // 4096 float4 per block, exact cover
#define G_HYP   (N_Z / (256 * 8))    // 216
#define G_TOTAL (G_GMM + G_MSE + G_HYP)   // 8856
#define SWIZZLE_PRIME 7919           // prime, !| 8856 -> bijective interleave

typedef float v4f __attribute__((ext_vector_type(4)));

// Branch-free Abramowitz & Stegun 7.1.26 erf, |abs err| <= 1.5e-7.
__device__ __forceinline__ float erf_fast(float x) {
    float ax = fabsf(x);
    float t  = __builtin_amdgcn_rcpf(fmaf(0.3275911f, ax, 1.0f));
    float p  = t * fmaf(t, fmaf(t, fmaf(t, fmaf(t, 1.061405429f,
                 -1.453152027f), 1.421413741f), -0.284496736f), 0.254829592f);
    float e  = __expf(-ax * ax);
    float r  = fmaf(-p, e, 1.0f);          // erf(|x|)
    return copysignf(r, x);
}

// Block (256 threads) reduction; thread 0 writes partial to slot.
__device__ __forceinline__ void block_write_partial(double* __restrict__ slot,
                                                    float val) {
    #pragma unroll
    for (int off = 32; off > 0; off >>= 1)
        val += __shfl_down(val, off, 64);
    __shared__ float smem[4];
    int lane = threadIdx.x & 63;
    int wid  = threadIdx.x >> 6;
    if (lane == 0) smem[wid] = val;
    __syncthreads();
    if (threadIdx.x == 0) {
        float s = smem[0] + smem[1] + smem[2] + smem[3];
        *slot = (double)s;
    }
}

// GMM rate:  logsumexp_k( logsoftmax(w)_k + log(pmf_k) ) collapsed to
//   rate_bits = log2(S) - log2(P) + 1,
//   S = sum e^(w-mw),  P = sum e^(w-mw) * max(erf(xu)-erf(xl), 2e-6)
__device__ __forceinline__ float gmm_rate(float y,
                                          float w0, float w1, float w2,
                                          float m0, float m1, float m2,
                                          float s0, float s1, float s2) {
    float mw = fmaxf(w0, fmaxf(w1, w2));
    float e0 = __expf(w0 - mw), e1 = __expf(w1 - mw), e2 = __expf(w2 - mw);
    float S = e0 + e1 + e2;

    float i0 = fminf(__expf(-s0), 1e5f) * INV_SQRT2;
    float i1 = fminf(__expf(-s1), 1e5f) * INV_SQRT2;
    float i2 = fminf(__expf(-s2), 1e5f) * INV_SQRT2;

    float yu = y + 0.5f, yl = y - 0.5f;

    float d0 = erf_fast((yu - m0) * i0) - erf_fast((yl - m0) * i0);
    float d1 = erf_fast((yu - m1) * i1) - erf_fast((yl - m1) * i1);
    float d2 = erf_fast((yu - m2) * i2) - erf_fast((yl - m2) * i2);

    float P = e0 * fmaxf(d0, 2e-6f);
    P = fmaf(e1, fmaxf(d1, 2e-6f), P);
    P = fmaf(e2, fmaxf(d2, 2e-6f), P);

    return __log2f(S) - __log2f(P) + 1.0f;
}

__global__ void __launch_bounds__(256)
fused_kernel(const float* __restrict__ x, const float* __restrict__ xh,
             const float* __restrict__ params, const float* __restrict__ y_hat,
             const float* __restrict__ z_hat, double* __restrict__ partial) {
    // Bijective swizzle interleaves work types across dispatch order; slots in
    // partial[] remain partitioned into 3 contiguous segments by work type.
    unsigned v = ((unsigned)blockIdx.x * SWIZZLE_PRIME) % G_TOTAL;

    if (v < G_GMM) {
        // ---- GMM latent rate: 4 elements/thread, 10 float4 loads in flight.
        // 40 data VGPRs + addressing stays <= 64 VGPR (full occupancy) while
        // every load issues before the first dependent waitcnt.
        int gid = v * 256 + threadIdx.x;             // float4 index into y
        int bc  = gid / (HW / 4);
        int hw4 = gid - bc * (HW / 4);
        const v4f* pp = (const v4f*)params + (size_t)bc * (9 * HW / 4) + hw4;

        v4f y4 = ((const v4f*)y_hat)[gid];
        v4f f0 = pp[0 * (HW / 4)];
        v4f f1 = pp[1 * (HW / 4)];
        v4f f2 = pp[2 * (HW / 4)];
        v4f f3 = pp[3 * (HW / 4)];
        v4f f4 = pp[4 * (HW / 4)];
        v4f f5 = pp[5 * (HW / 4)];
        v4f f6 = pp[6 * (HW / 4)];
        v4f f7 = pp[7 * (HW / 4)];
        v4f f8 = pp[8 * (HW / 4)];

        float r = 0.0f;
        #pragma unroll
        for (int c = 0; c < 4; ++c)
            r += gmm_rate(y4[c], f0[c], f1[c], f2[c],
                          f3[c], f4[c], f5[c],
                          f6[c], f7[c], f8[c]);
        block_write_partial(&partial[v], r);
    } else if (v < G_GMM + G_MSE) {
        // ---- MSE: contiguous 4096-float4 chunk per block, 8 loads/iter ----
        // x/x_hat are read-once streams: nontemporal, keep LLC for params.
        int mb = v - G_GMM;
        const v4f* x4  = (const v4f*)x;
        const v4f* xh4 = (const v4f*)xh;
        size_t base = (size_t)mb * 4096 + threadIdx.x;
        float a0 = 0.f, a1 = 0.f, a2 = 0.f, a3 = 0.f;
        #pragma unroll
        for (int it = 0; it < 4; ++it) {
            size_t b0 = base + (size_t)it * 1024;
            v4f p0 = __builtin_nontemporal_load(x4  + b0);
            v4f p1 = __builtin_nontemporal_load(x4  + b0 + 256);
            v4f p2 = __builtin_nontemporal_load(x4  + b0 + 512);
            v4f p3 = __builtin_nontemporal_load(x4  + b0 + 768);
            v4f q0 = __builtin_nontemporal_load(xh4 + b0);
            v4f q1 = __builtin_nontemporal_load(xh4 + b0 + 256);
            v4f q2 = __builtin_nontemporal_load(xh4 + b0 + 512);
            v4f q3 = __builtin_nontemporal_load(xh4 + b0 + 768);
            v4f d0 = q0 - p0, d1 = q1 - p1, d2 = q2 - p2, d3 = q3 - p3;
            a0 += d0.x*d0.x + d0.y*d0.y + d0.z*d0.z + d0.w*d0.w;
            a1 += d1.x*d1.x + d1.y*d1.y + d1.z*d1.z + d1.w*d1.w;
            a2 += d2.x*d2.x + d2.y*d2.y + d2.z*d2.z + d2.w*d2.w;
            a3 += d3.x*d3.x + d3.y*d3.y + d3.z*d3.z + d3.w*d3.w;
        }
        block_write_partial(&partial[v], (a0 + a1) + (a2 + a3));
    } else {
        // ---- Hyperlatent rate: 8 elements/thread --------------------------
        int hb = v - G_GMM - G_MSE;
        int g  = hb * 512 + threadIdx.x;
        v4f z0 = ((const v4f*)z_hat)[g];
        v4f z1 = ((const v4f*)z_hat)[g + 256];
        float r = 0.0f;
        #pragma unroll
        for (int j = 0; j < 8; ++j) {
            float z = (j < 4) ? z0[j] : z1[j - 4];
            float d = erf_fast((z + 0.5f) * INV_SQRT2)
                    - erf_fast((z - 0.5f) * INV_SQRT2);
            r += 1.0f - __log2f(fmaxf(d, 2e-6f));
        }
        block_write_partial(&partial[v], r);
    }
}

// Reduce partial segments: [0,G_GMM)=rate_y, [G_GMM,+G_MSE)=sq_err,
// [G_GMM+G_MSE,G_TOTAL)=rate_z.
__global__ void __launch_bounds__(256)
finalize_kernel(const double* __restrict__ partial, float* __restrict__ out) {
    __shared__ double sm[256];
    double seg[3];
    const int lo[3] = {0, G_GMM, G_GMM + G_MSE};
    const int hi[3] = {G_GMM, G_GMM + G_MSE, G_TOTAL};
    for (int k = 0; k < 3; ++k) {
        double a = 0.0;
        for (int i = lo[k] + threadIdx.x; i < hi[k]; i += 256) a += partial[i];
        sm[threadIdx.x] = a;
        __syncthreads();
        for (int off = 128; off > 0; off >>= 1) {
            if (threadIdx.x < (unsigned)off) sm[threadIdx.x] += sm[threadIdx.x + off];
            __syncthreads();
        }
        seg[k] = sm[0];
        __syncthreads();
    }
    if (threadIdx.x == 0) {
        double rate_y     = seg[0];
        double sq_err     = seg[1];
        double rate_z     = seg[2];
        double distortion = sq_err / (double)N_X;
        double bpp = (rate_y / (double)BB + rate_z / (double)BB) / (double)NUM_PIXELS;
        double loss = 0.01 * 255.0 * 255.0 * distortion + bpp;
        out[0] = (float)loss;
        out[1] = (float)distortion;
        out[2] = (float)bpp;
    }
}

extern "C" void kernel_launch(void* const* d_in, const int* in_sizes, int n_in,
                              void* d_out, int out_size, void* d_ws, size_t ws_size,
                              hipStream_t stream) {
    const float* x      = (const float*)d_in[0];
    const float* x_hat  = (const float*)d_in[1];
    const float* params = (const float*)d_in[2];
    const float* y_hat  = (const float*)d_in[3];
    const float* z_hat  = (const float*)d_in[4];
    float* out = (float*)d_out;
    double* partial = (double*)d_ws;   // G_TOTAL doubles, all written each call

    fused_kernel<<<G_TOTAL, 256, 0, stream>>>(x, x_hat, params, y_hat, z_hat, partial);
    finalize_kernel<<<1, 256, 0, stream>>>(partial, out);
}

// Round 2
// 504.339 us; speedup vs baseline: 1.0005x; 1.0005x over previous
//
#include <hip/hip_runtime.h>
#include <math.h>

// Problem constants (from reference setup_inputs)
#define BB 16
#define CC 192
#define KK 3
#define HH 48
#define WW 48
#define HW (HH * WW)                 // 2304
#define N_Y (BB * CC * HW)           // 7,077,888
#define IMG 768
#define N_X (BB * 3 * IMG * IMG)     // 28,311,552
#define N_Z (BB * CC * 12 * 12)      // 442,368
#define NUM_PIXELS (BB * IMG * IMG)  // 9,437,184

#define INV_SQRT2 0.7071067811865476f

// Fused grid partition (256 threads/block)
// GMM: 4 elements/thread (ONE float4 row). Rounds 0/1 both reported
// VGPR_Count=36 (< 40 needed for 10 concurrent float4 results) -> the
// compiler provably serialized the load batch; kernel ran latency-bound at
// 21% HBM / 20% VALU. This version FORCES load clustering with
// __builtin_amdgcn_sched_barrier(0) fences (loads before fence, consumers
// after). Verification signal: VGPR_Count must rise to ~64+.
#define G_GMM   (N_Y / (256 * 4))    // 6912
#define G_MSE   1728                 // 4096 float4 per block, exact cover
#define G_HYP   (N_Z / (256 * 8))    // 216
#define G_TOTAL (G_GMM + G_MSE + G_HYP)   // 8856
#define SWIZZLE_PRIME 7919           // prime, !| 8856 -> bijective interleave

typedef float v4f __attribute__((ext_vector_type(4)));

// Branch-free Abramowitz & Stegun 7.1.26 erf, |abs err| <= 1.5e-7.
__device__ __forceinline__ float erf_fast(float x) {
    float ax = fabsf(x);
    float t  = __builtin_amdgcn_rcpf(fmaf(0.3275911f, ax, 1.0f));
    float p  = t * fmaf(t, fmaf(t, fmaf(t, fmaf(t, 1.061405429f,
                 -1.453152027f), 1.421413741f), -0.284496736f), 0.254829592f);
    float e  = __expf(-ax * ax);
    float r  = fmaf(-p, e, 1.0f);          // erf(|x|)
    return copysignf(r, x);
}

// Block (256 threads) reduction; thread 0 writes partial to slot.
__device__ __forceinline__ void block_write_partial(double* __restrict__ slot,
                                                    float val) {
    #pragma unroll
    for (int off = 32; off > 0; off >>= 1)
        val += __shfl_down(val, off, 64);
    __shared__ float smem[4];
    int lane = threadIdx.x & 63;
    int wid  = threadIdx.x >> 6;
    if (lane == 0) smem[wid] = val;
    __syncthreads();
    if (threadIdx.x == 0) {
        float s = smem[0] + smem[1] + smem[2] + smem[3];
        *slot = (double)s;
    }
}

// GMM rate:  logsumexp_k( logsoftmax(w)_k + log(pmf_k) ) collapsed to
//   rate_bits = log2(S) - log2(P) + 1,
//   S = sum e^(w-mw),  P = sum e^(w-mw) * max(erf(xu)-erf(xl), 2e-6)
__device__ __forceinline__ float gmm_rate(float y,
                                          float w0, float w1, float w2,
                                          float m0, float m1, float m2,
                                          float s0, float s1, float s2) {
    float mw = fmaxf(w0, fmaxf(w1, w2));
    float e0 = __expf(w0 - mw), e1 = __expf(w1 - mw), e2 = __expf(w2 - mw);
    float S = e0 + e1 + e2;

    float i0 = fminf(__expf(-s0), 1e5f) * INV_SQRT2;
    float i1 = fminf(__expf(-s1), 1e5f) * INV_SQRT2;
    float i2 = fminf(__expf(-s2), 1e5f) * INV_SQRT2;

    float yu = y + 0.5f, yl = y - 0.5f;

    float d0 = erf_fast((yu - m0) * i0) - erf_fast((yl - m0) * i0);
    float d1 = erf_fast((yu - m1) * i1) - erf_fast((yl - m1) * i1);
    float d2 = erf_fast((yu - m2) * i2) - erf_fast((yl - m2) * i2);

    float P = e0 * fmaxf(d0, 2e-6f);
    P = fmaf(e1, fmaxf(d1, 2e-6f), P);
    P = fmaf(e2, fmaxf(d2, 2e-6f), P);

    return __log2f(S) - __log2f(P) + 1.0f;
}

__global__ void __launch_bounds__(256)
fused_kernel(const float* __restrict__ x, const float* __restrict__ xh,
             const float* __restrict__ params, const float* __restrict__ y_hat,
             const float* __restrict__ z_hat, double* __restrict__ partial) {
    // Bijective swizzle interleaves work types across dispatch order; slots in
    // partial[] remain partitioned into 3 contiguous segments by work type.
    unsigned v = ((unsigned)blockIdx.x * SWIZZLE_PRIME) % G_TOTAL;

    if (v < G_GMM) {
        // ---- GMM latent rate: 10 float4 loads forced into flight ----------
        int gid = v * 256 + threadIdx.x;             // float4 index into y
        int bc  = gid / (HW / 4);
        int hw4 = gid - bc * (HW / 4);
        const v4f* pp = (const v4f*)params + (size_t)bc * (9 * HW / 4) + hw4;

        v4f y4 = ((const v4f*)y_hat)[gid];
        v4f f0 = pp[0 * (HW / 4)];
        v4f f1 = pp[1 * (HW / 4)];
        v4f f2 = pp[2 * (HW / 4)];
        v4f f3 = pp[3 * (HW / 4)];
        v4f f4 = pp[4 * (HW / 4)];
        v4f f5 = pp[5 * (HW / 4)];
        v4f f6 = pp[6 * (HW / 4)];
        v4f f7 = pp[7 * (HW / 4)];
        v4f f8 = pp[8 * (HW / 4)];
        // Nothing (especially not the erf/exp compute) may be hoisted above
        // this point: all 10 loads issue back-to-back, single waitcnt chain.
        __builtin_amdgcn_sched_barrier(0);

        float r = 0.0f;
        #pragma unroll
        for (int c = 0; c < 4; ++c)
            r += gmm_rate(y4[c], f0[c], f1[c], f2[c],
                          f3[c], f4[c], f5[c],
                          f6[c], f7[c], f8[c]);
        block_write_partial(&partial[v], r);
    } else if (v < G_GMM + G_MSE) {
        // ---- MSE: 2-deep software pipeline, named A/B batches -------------
        // NT loads never allocate in cache -> full HBM latency every time;
        // keep 8-16 KB per wave in flight. Static register naming (no
        // runtime-indexed arrays -> no scratch).
        int mb = v - G_GMM;
        const v4f* x4  = (const v4f*)x;
        const v4f* xh4 = (const v4f*)xh;
        size_t b = (size_t)mb * 4096 + threadIdx.x;
        float a0 = 0.f, a1 = 0.f, a2 = 0.f, a3 = 0.f;

        #define NT(P, OFF) __builtin_nontemporal_load((P) + (OFF))
        // batch 0 -> A, batch 1 -> B
        v4f pa0 = NT(x4,  b);        v4f pa1 = NT(x4,  b + 256);
        v4f pa2 = NT(x4,  b + 512);  v4f pa3 = NT(x4,  b + 768);
        v4f qa0 = NT(xh4, b);        v4f qa1 = NT(xh4, b + 256);
        v4f qa2 = NT(xh4, b + 512);  v4f qa3 = NT(xh4, b + 768);
        v4f pb0 = NT(x4,  b + 1024); v4f pb1 = NT(x4,  b + 1280);
        v4f pb2 = NT(x4,  b + 1536); v4f pb3 = NT(x4,  b + 1792);
        v4f qb0 = NT(xh4, b + 1024); v4f qb1 = NT(xh4, b + 1280);
        v4f qb2 = NT(xh4, b + 1536); v4f qb3 = NT(xh4, b + 1792);
        __builtin_amdgcn_sched_barrier(0);

        {   // consume batch 0 (A); prefetch batch 2 into A
            v4f d0 = qa0 - pa0, d1 = qa1 - pa1, d2 = qa2 - pa2, d3 = qa3 - pa3;
            a0 += d0.x*d0.x + d0.y*d0.y + d0.z*d0.z + d0.w*d0.w;
            a1 += d1.x*d1.x + d1.y*d1.y + d1.z*d1.z + d1.w*d1.w;
            a2 += d2.x*d2.x + d2.y*d2.y + d2.z*d2.z + d2.w*d2.w;
            a3 += d3.x*d3.x + d3.y*d3.y + d3.z*d3.z + d3.w*d3.w;
            pa0 = NT(x4,  b + 2048); pa1 = NT(x4,  b + 2304);
            pa2 = NT(x4,  b + 2560); pa3 = NT(x4,  b + 2816);
            qa0 = NT(xh4, b + 2048); qa1 = NT(xh4, b + 2304);
            qa2 = NT(xh4, b + 2560); qa3 = NT(xh4, b + 2816);
        }
        __builtin_amdgcn_sched_barrier(0);
        {   // consume batch 1 (B); prefetch batch 3 into B
            v4f d0 = qb0 - pb0, d1 = qb1 - pb1, d2 = qb2 - pb2, d3 = qb3 - pb3;
            a0 += d0.x*d0.x + d0.y*d0.y + d0.z*d0.z + d0.w*d0.w;
            a1 += d1.x*d1.x + d1.y*d1.y + d1.z*d1.z + d1.w*d1.w;
            a2 += d2.x*d2.x + d2.y*d2.y + d2.z*d2.z + d2.w*d2.w;
            a3 += d3.x*d3.x + d3.y*d3.y + d3.z*d3.z + d3.w*d3.w;
            pb0 = NT(x4,  b + 3072); pb1 = NT(x4,  b + 3328);
            pb2 = NT(x4,  b + 3584); pb3 = NT(x4,  b + 3840);
            qb0 = NT(xh4, b + 3072); qb1 = NT(xh4, b + 3328);
            qb2 = NT(xh4, b + 3584); qb3 = NT(xh4, b + 3840);
        }
        __builtin_amdgcn_sched_barrier(0);
        {   // consume batch 2 (A)
            v4f d0 = qa0 - pa0, d1 = qa1 - pa1, d2 = qa2 - pa2, d3 = qa3 - pa3;
            a0 += d0.x*d0.x + d0.y*d0.y + d0.z*d0.z + d0.w*d0.w;
            a1 += d1.x*d1.x + d1.y*d1.y + d1.z*d1.z + d1.w*d1.w;
            a2 += d2.x*d2.x + d2.y*d2.y + d2.z*d2.z + d2.w*d2.w;
            a3 += d3.x*d3.x + d3.y*d3.y + d3.z*d3.z + d3.w*d3.w;
        }
        {   // consume batch 3 (B)
            v4f d0 = qb0 - pb0, d1 = qb1 - pb1, d2 = qb2 - pb2, d3 = qb3 - pb3;
            a0 += d0.x*d0.x + d0.y*d0.y + d0.z*d0.z + d0.w*d0.w;
            a1 += d1.x*d1.x + d1.y*d1.y + d1.z*d1.z + d1.w*d1.w;
            a2 += d2.x*d2.x + d2.y*d2.y + d2.z*d2.z + d2.w*d2.w;
            a3 += d3.x*d3.x + d3.y*d3.y + d3.z*d3.z + d3.w*d3.w;
        }
        #undef NT
        block_write_partial(&partial[v], (a0 + a1) + (a2 + a3));
    } else {
        // ---- Hyperlatent rate: 8 elements/thread --------------------------
        int hb = v - G_GMM - G_MSE;
        int g  = hb * 512 + threadIdx.x;
        v4f z0 = ((const v4f*)z_hat)[g];
        v4f z1 = ((const v4f*)z_hat)[g + 256];
        __builtin_amdgcn_sched_barrier(0);
        float r = 0.0f;
        #pragma unroll
        for (int j = 0; j < 8; ++j) {
            float z = (j < 4) ? z0[j] : z1[j - 4];
            float d = erf_fast((z + 0.5f) * INV_SQRT2)
                    - erf_fast((z - 0.5f) * INV_SQRT2);
            r += 1.0f - __log2f(fmaxf(d, 2e-6f));
        }
        block_write_partial(&partial[v], r);
    }
}

// Reduce partial segments: [0,G_GMM)=rate_y, [G_GMM,+G_MSE)=sq_err,
// [G_GMM+G_MSE,G_TOTAL)=rate_z.
__global__ void __launch_bounds__(256)
finalize_kernel(const double* __restrict__ partial, float* __restrict__ out) {
    __shared__ double sm[256];
    double seg[3];
    const int lo[3] = {0, G_GMM, G_GMM + G_MSE};
    const int hi[3] = {G_GMM, G_GMM + G_MSE, G_TOTAL};
    for (int k = 0; k < 3; ++k) {
        double a = 0.0;
        for (int i = lo[k] + threadIdx.x; i < hi[k]; i += 256) a += partial[i];
        sm[threadIdx.x] = a;
        __syncthreads();
        for (int off = 128; off > 0; off >>= 1) {
            if (threadIdx.x < (unsigned)off) sm[threadIdx.x] += sm[threadIdx.x + off];
            __syncthreads();
        }
        seg[k] = sm[0];
        __syncthreads();
    }
    if (threadIdx.x == 0) {
        double rate_y     = seg[0];
        double sq_err     = seg[1];
        double rate_z     = seg[2];
        double distortion = sq_err / (double)N_X;
        double bpp = (rate_y / (double)BB + rate_z / (double)BB) / (double)NUM_PIXELS;
        double loss = 0.01 * 255.0 * 255.0 * distortion + bpp;
        out[0] = (float)loss;
        out[1] = (float)distortion;
        out[2] = (float)bpp;
    }
}

extern "C" void kernel_launch(void* const* d_in, const int* in_sizes, int n_in,
                              void* d_out, int out_size, void* d_ws, size_t ws_size,
                              hipStream_t stream) {
    const float* x      = (const float*)d_in[0];
    const float* x_hat  = (const float*)d_in[1];
    const float* params = (const float*)d_in[2];
    const float* y_hat  = (const float*)d_in[3];
    const float* z_hat  = (const float*)d_in[4];
    float* out = (float*)d_out;
    double* partial = (double*)d_ws;   // G_TOTAL doubles, all written each call

    fused_kernel<<<G_TOTAL, 256, 0, stream>>>(x, x_hat, params, y_hat, z_hat, partial);
    finalize_kernel<<<1, 256, 0, stream>>>(partial, out);
}